// Round 12
// baseline (221.205 us; speedup 1.0000x reference)
//
#include <hip/hip_runtime.h>
#include <stdint.h>

#define N_NODES 50000
#define N_REL   3
#define D       128
#define N_EDGES 600000
#define NPAD    50016              // per-relation stride for off/deg arrays
#define BK_SHIFT 8                 // bucket covers 256 nodes (R11: 1024 -> placeB 0.57 blk/CU)
#define NBK     196                // ceil(50000/256)
#define NCHUNK  256                // edge chunks per relation
#define CH_EDGES 2344              // 256*2344 = 600064 >= N_EDGES
#define CH_CAP  32                 // slots per (chunk,bin); mean 12.0, +5.8 sigma
#define OVF_CAP 8192               // per-rel overflow list (expected use: ~0)
#define REG_CAP 4096               // srt records per (rel,bucket) region (mean 3061, +18 sigma)

typedef unsigned int   uint;
typedef unsigned short ushort_t;
typedef __attribute__((ext_vector_type(8))) short short8v;  // 8 bf16 (MFMA A/B frag)
typedef __attribute__((ext_vector_type(4))) float f32x4;    // MFMA C/D frag

// fp32 -> bf16 round-to-nearest-even
__device__ __forceinline__ ushort_t f2bf(float f)
{
    uint u = __float_as_uint(f);
    u += 0x7FFFu + ((u >> 16) & 1u);
    return (ushort_t)(u >> 16);
}
__device__ __forceinline__ float bf_lo(uint u) { return __uint_as_float(u << 16); }
__device__ __forceinline__ float bf_hi(uint u) { return __uint_as_float(u & 0xFFFF0000u); }

// ---------------------------------------------------------------------------
__global__ __launch_bounds__(256) void zero_cnt(int* __restrict__ p, int n)
{
    const int i = blockIdx.x * 256 + threadIdx.x;
    if (i < n) p[i] = 0;
}

// ---------------------------------------------------------------------------
// cvtW: Wt[r][n][k] = bf16(W[r][k][n])
// ---------------------------------------------------------------------------
__global__ __launch_bounds__(256) void cvtW(const float* __restrict__ W,
                                            ushort_t* __restrict__ Wt)
{
    const int idx = blockIdx.x * 256 + threadIdx.x;
    if (idx >= N_REL * D * D) return;
    const int r   = idx >> 14;
    const int rem = idx & 16383;
    const int n   = rem >> 7;
    const int k   = rem & 127;
    Wt[idx] = f2bf(W[r * 16384 + k * 128 + n]);
}

// ---------------------------------------------------------------------------
// GEMM (MFMA bf16, unchanged -- R11 proved absmax-neutral at 0.125):
// 64x128 tile, whole K in LDS, 4 waves x 32 MFMA. Verified m89/m91 layouts.
// ---------------------------------------------------------------------------
__global__ __launch_bounds__(256, 3) void wh_gemm(
    const float* __restrict__ x, const ushort_t* __restrict__ Wt_all,
    const float* __restrict__ b, ushort_t* __restrict__ wh_all)
{
    __shared__ ushort_t xs[64][136];
    __shared__ ushort_t wt[128][136];

    const int r = blockIdx.y;
    const ushort_t* Wt = Wt_all + (size_t)r * D * D;
    const float* br = b + (size_t)r * D;
    ushort_t* wh = wh_all + (size_t)r * N_NODES * D;

    const int tid  = threadIdx.x;
    const int lane = tid & 63;
    const int w    = tid >> 6;
    const int row0 = blockIdx.x * 64;

    #pragma unroll
    for (int i = 0; i < 8; ++i) {
        const int idx = i * 256 + tid;
        const int rr  = idx >> 5;
        const int c4  = idx & 31;
        const int gr  = row0 + rr;
        float4 v = make_float4(0.f, 0.f, 0.f, 0.f);
        if (gr < N_NODES) v = *(const float4*)(x + (size_t)gr * D + c4 * 4);
        ushort4 o;
        o.x = f2bf(v.x); o.y = f2bf(v.y); o.z = f2bf(v.z); o.w = f2bf(v.w);
        *(ushort4*)&xs[rr][c4 * 4] = o;
    }
    #pragma unroll
    for (int i = 0; i < 8; ++i) {
        const int idx = i * 256 + tid;
        const int n   = idx >> 4;
        const int k8  = idx & 15;
        const uint4 v = *(const uint4*)(Wt + n * D + k8 * 8);
        *(uint4*)&wt[n][k8 * 8] = v;
    }
    __syncthreads();

    const int rl = lane & 15;
    const int kg = lane >> 4;

    f32x4 acc[4][2];
    #pragma unroll
    for (int m = 0; m < 4; ++m)
        #pragma unroll
        for (int n = 0; n < 2; ++n) acc[m][n] = (f32x4){0.f, 0.f, 0.f, 0.f};

    #pragma unroll
    for (int ks = 0; ks < 4; ++ks) {
        short8v a[4], bb[2];
        #pragma unroll
        for (int m = 0; m < 4; ++m)
            a[m] = *(const short8v*)&xs[m * 16 + rl][ks * 32 + kg * 8];
        #pragma unroll
        for (int n = 0; n < 2; ++n)
            bb[n] = *(const short8v*)&wt[w * 32 + n * 16 + rl][ks * 32 + kg * 8];
        #pragma unroll
        for (int m = 0; m < 4; ++m)
            #pragma unroll
            for (int n = 0; n < 2; ++n)
                acc[m][n] = __builtin_amdgcn_mfma_f32_16x16x32_bf16(
                    a[m], bb[n], acc[m][n], 0, 0, 0);
    }

    #pragma unroll
    for (int n = 0; n < 2; ++n) {
        const int col = w * 32 + n * 16 + rl;
        const float bias = br[col];
        #pragma unroll
        for (int m = 0; m < 4; ++m)
            #pragma unroll
            for (int q = 0; q < 4; ++q) {
                const int grow = row0 + m * 16 + kg * 4 + q;
                if (grow < N_NODES)
                    wh[(size_t)grow * D + col] = f2bf(acc[m][n][q] + bias);
            }
    }
}

// ---------------------------------------------------------------------------
// bucketA2: deterministic bucketing -- zero global atomics on the hot path
// (R8 lesson: shared cursors serialize cross-XCD). Block = (chunk, rel):
// bins CH_EDGES edges in LDS by dst>>8 (196 bins), flushes bin b to the
// private region bkt[rel][b][chunk][0..n), ccnt written UNCONDITIONALLY
// (empty bin must clear poison). Record = (dst<<16)|src.
// ---------------------------------------------------------------------------
__global__ __launch_bounds__(256) void bucketA2(const int* __restrict__ src,
                                                const int* __restrict__ dst,
                                                uint* __restrict__ bkt,
                                                int* __restrict__ ccnt,
                                                uint* __restrict__ ovf,
                                                int* __restrict__ ovf_cnt)
{
    __shared__ uint bins[NBK][CH_CAP];   // 25.1 KB
    __shared__ int bcnt[NBK];

    const int r   = blockIdx.y;
    const int ch  = blockIdx.x;
    const int tid = threadIdx.x;

    for (int i = tid; i < NBK; i += 256) bcnt[i] = 0;
    __syncthreads();

    const int* srcr = src + (size_t)r * N_EDGES;
    const int* dstr = dst + (size_t)r * N_EDGES;
    const int e0 = ch * CH_EDGES;
    const int e1 = min(e0 + CH_EDGES, N_EDGES);

    for (int e = e0 + tid; e < e1; e += 256) {
        const uint d = (uint)dstr[e];
        const uint s = (uint)srcr[e];
        const int cb = (int)(d >> BK_SHIFT);
        const uint rec = (d << 16) | s;
        const int lp = atomicAdd(&bcnt[cb], 1);
        if (lp < CH_CAP) {
            bins[cb][lp] = rec;
        } else {  // ~never (+5.8 sigma); correctness net
            const int p = atomicAdd(&ovf_cnt[r], 1);
            ovf[(size_t)r * OVF_CAP + p] = rec;
        }
    }
    __syncthreads();

    const int lane = tid & 63, wid = tid >> 6;
    for (int bin = wid; bin < NBK; bin += 4) {
        const int n = min(bcnt[bin], CH_CAP);
        if (lane == 0) ccnt[(r * NBK + bin) * NCHUNK + ch] = n;  // ALWAYS write
        if (n == 0) continue;
        uint* dp = bkt + ((size_t)(r * NBK + bin) * NCHUNK + ch) * CH_CAP;
        for (int i = lane; i < n; i += 64) dp[i] = bins[bin][i];
    }
}

// ---------------------------------------------------------------------------
// placeB2: per (rel, 256-node bucket) block -- grid (196,3)=588 blocks of 256
// threads (R11 lesson: 147x1024 = 0.57 blk/CU starved 109 CUs). Valid-prefix
// iteration: each 32-lane half-wave walks one chunk's valid records only
// (skips the ~62% empty slots). hist -> scan(256) -> off/deg -> place.
// ---------------------------------------------------------------------------
__global__ __launch_bounds__(256) void placeB2(const uint* __restrict__ bkt,
                                               const int* __restrict__ ccnt,
                                               const uint* __restrict__ ovf,
                                               const int* __restrict__ ovf_cnt,
                                               int* __restrict__ off,
                                               int* __restrict__ deg,
                                               int* __restrict__ srt)
{
    __shared__ int hcnt[256];
    __shared__ int pcur[256];
    __shared__ int ccl[NCHUNK];
    __shared__ int wtot[4], wexc[4];

    const int bx        = blockIdx.x;
    const int r         = blockIdx.y;
    const int region    = r * NBK + bx;
    const size_t rbase  = (size_t)region * REG_CAP;
    const int node_base = bx << BK_SHIFT;
    const int tid       = threadIdx.x;
    const int lane      = tid & 63;
    const int wid       = tid >> 6;
    const int hw        = tid >> 5;   // half-wave id (0..7)
    const int l32       = tid & 31;

    hcnt[tid] = 0;
    ccl[tid] = ccnt[region * NCHUNK + tid];   // NCHUNK == 256 == blockDim
    __syncthreads();

    const uint* bb  = bkt + (size_t)region * (NCHUNK * CH_CAP);
    const int   nov = ovf_cnt[r];
    const uint* ovr = ovf + (size_t)r * OVF_CAP;

    // pass 1: histogram over valid prefixes only
    for (int ch = hw; ch < NCHUNK; ch += 8) {
        const int n = ccl[ch];
        for (int i = l32; i < n; i += 32)
            atomicAdd(&hcnt[(bb[ch * CH_CAP + i] >> 16) & 255], 1);
    }
    for (int j = tid; j < nov; j += 256) {
        const uint d = ovr[j] >> 16;
        if ((int)(d >> BK_SHIFT) == bx) atomicAdd(&hcnt[d & 255], 1);
    }
    __syncthreads();

    // exclusive scan of 256 counts (4 waves)
    const int orig = hcnt[tid];
    int v = orig;
    #pragma unroll
    for (int s = 1; s < 64; s <<= 1) {
        const int t = __shfl_up(v, s, 64);
        if (lane >= s) v += t;
    }
    if (lane == 63) wtot[wid] = v;
    __syncthreads();
    if (tid == 0) {
        int run = 0;
        #pragma unroll
        for (int w = 0; w < 4; ++w) { const int t = wtot[w]; wexc[w] = run; run += t; }
    }
    __syncthreads();
    const int excl = wexc[wid] + (v - orig);

    const int node = node_base + tid;
    if (node < N_NODES) {
        off[r * NPAD + node] = (int)rbase + excl;
        deg[r * NPAD + node] = orig;
    }
    pcur[tid] = excl;
    __syncthreads();

    // pass 2: place (scattered writes stay inside this region's L2-hot window)
    for (int ch = hw; ch < NCHUNK; ch += 8) {
        const int n = ccl[ch];
        for (int i = l32; i < n; i += 32) {
            const uint rec = bb[ch * CH_CAP + i];
            const int p = atomicAdd(&pcur[(rec >> 16) & 255], 1);
            srt[rbase + p] = (int)(rec & 0xFFFFu);
        }
    }
    for (int j = tid; j < nov; j += 256) {
        const uint rec = ovr[j];
        const uint d = rec >> 16;
        if ((int)(d >> BK_SHIFT) == bx) {
            const int p = atomicAdd(&pcur[d & 255], 1);
            srt[rbase + p] = (int)(rec & 0xFFFFu);
        }
    }
}

// ---------------------------------------------------------------------------
// Aggregate (bf16 gather): 16 lanes per dst node, each owns 8 columns.
// fp32 accum; single store per node. NEW: 4-deep edge unroll (more loads in
// flight on the L2-miss path; R11: VALUBusy 28%, hbm 41% -> latency headroom).
// ---------------------------------------------------------------------------
__global__ __launch_bounds__(256) void aggregate(const ushort_t* __restrict__ wh_all,
                                                 const int* __restrict__ off,
                                                 const int* __restrict__ deg,
                                                 const int* __restrict__ srt,
                                                 float* __restrict__ out)
{
    const int g    = (blockIdx.x * 256 + threadIdx.x) >> 4;
    const int lane = threadIdx.x & 15;
    if (g >= N_NODES) return;

    float acc[8];
    #pragma unroll
    for (int j = 0; j < 8; ++j) acc[j] = 0.0f;

    for (int r = 0; r < N_REL; ++r) {
        const ushort_t* wh = wh_all + (size_t)r * N_NODES * D;
        const int e0 = off[r * NPAD + g];
        const int e1 = e0 + deg[r * NPAD + g];
        int i = e0;
        for (; i + 4 <= e1; i += 4) {
            const int s0 = srt[i + 0];
            const int s1 = srt[i + 1];
            const int s2 = srt[i + 2];
            const int s3 = srt[i + 3];
            const uint4 v0 = *(const uint4*)(wh + (size_t)s0 * D + lane * 8);
            const uint4 v1 = *(const uint4*)(wh + (size_t)s1 * D + lane * 8);
            const uint4 v2 = *(const uint4*)(wh + (size_t)s2 * D + lane * 8);
            const uint4 v3 = *(const uint4*)(wh + (size_t)s3 * D + lane * 8);
            acc[0] += bf_lo(v0.x); acc[1] += bf_hi(v0.x);
            acc[2] += bf_lo(v0.y); acc[3] += bf_hi(v0.y);
            acc[4] += bf_lo(v0.z); acc[5] += bf_hi(v0.z);
            acc[6] += bf_lo(v0.w); acc[7] += bf_hi(v0.w);
            acc[0] += bf_lo(v1.x); acc[1] += bf_hi(v1.x);
            acc[2] += bf_lo(v1.y); acc[3] += bf_hi(v1.y);
            acc[4] += bf_lo(v1.z); acc[5] += bf_hi(v1.z);
            acc[6] += bf_lo(v1.w); acc[7] += bf_hi(v1.w);
            acc[0] += bf_lo(v2.x); acc[1] += bf_hi(v2.x);
            acc[2] += bf_lo(v2.y); acc[3] += bf_hi(v2.y);
            acc[4] += bf_lo(v2.z); acc[5] += bf_hi(v2.z);
            acc[6] += bf_lo(v2.w); acc[7] += bf_hi(v2.w);
            acc[0] += bf_lo(v3.x); acc[1] += bf_hi(v3.x);
            acc[2] += bf_lo(v3.y); acc[3] += bf_hi(v3.y);
            acc[4] += bf_lo(v3.z); acc[5] += bf_hi(v3.z);
            acc[6] += bf_lo(v3.w); acc[7] += bf_hi(v3.w);
        }
        for (; i < e1; ++i) {
            const int s0 = srt[i];
            const uint4 v0 = *(const uint4*)(wh + (size_t)s0 * D + lane * 8);
            acc[0] += bf_lo(v0.x); acc[1] += bf_hi(v0.x);
            acc[2] += bf_lo(v0.y); acc[3] += bf_hi(v0.y);
            acc[4] += bf_lo(v0.z); acc[5] += bf_hi(v0.z);
            acc[6] += bf_lo(v0.w); acc[7] += bf_hi(v0.w);
        }
    }

    float* o = out + (size_t)g * D + lane * 8;
    *(float4*)(o + 0) = make_float4(acc[0], acc[1], acc[2], acc[3]);
    *(float4*)(o + 4) = make_float4(acc[4], acc[5], acc[6], acc[7]);
}

extern "C" void kernel_launch(void* const* d_in, const int* in_sizes, int n_in,
                              void* d_out, int out_size, void* d_ws, size_t ws_size,
                              hipStream_t stream)
{
    const float* x   = (const float*)d_in[0];
    const float* W   = (const float*)d_in[1];
    const float* b   = (const float*)d_in[2];
    const int*   src = (const int*)d_in[3];
    const int*   dst = (const int*)d_in[4];
    float* out = (float*)d_out;

    const int gemm_gx = (N_NODES + 63) / 64;          // 782
    const int agg_gx  = (N_NODES * 16 + 255) / 256;   // 3125
    const int L       = N_REL * NPAD;                 // 150048
    const int NREG    = N_REL * NBK;                  // 588

    // Workspace layout (~69.3 MB; ws proven >= 93 MB):
    char* base    = (char*)d_ws;
    ushort_t* wh  = (ushort_t*)base;                               // 38.4 MB
    int* off      = (int*)(base + (size_t)N_REL * N_NODES * D * 2);// L ints
    int* deg      = off + L;                                       // L ints
    int* ovf_cnt  = deg + L;                                       // 16 ints
    uint* ovf     = (uint*)(ovf_cnt + 16);                         // 3*8192 uints
    int* ccnt     = (int*)(ovf + (size_t)N_REL * OVF_CAP);         // 588*256 ints
    uint* bkt     = (uint*)(ccnt + NREG * NCHUNK);                 // 19.3 MB
    int*  srt     = (int*)(bkt + (size_t)NREG * NCHUNK * CH_CAP);  // 9.6 MB
    ushort_t* Wt  = (ushort_t*)(srt + (size_t)NREG * REG_CAP);     // 96 KB

    cvtW<<<(N_REL * D * D + 255) / 256, 256, 0, stream>>>(W, Wt);
    wh_gemm<<<dim3(gemm_gx, N_REL), 256, 0, stream>>>(x, Wt, b, wh);
    zero_cnt<<<1, 256, 0, stream>>>(ovf_cnt, 16);
    bucketA2<<<dim3(NCHUNK, N_REL), 256, 0, stream>>>(src, dst, bkt, ccnt, ovf, ovf_cnt);
    placeB2<<<dim3(NBK, N_REL), 256, 0, stream>>>(bkt, ccnt, ovf, ovf_cnt, off, deg, srt);
    aggregate<<<agg_gx, 256, 0, stream>>>(wh, off, deg, srt, out);
}